// Round 13
// baseline (1065.071 us; speedup 1.0000x reference)
//
#include <hip/hip_runtime.h>

#define CNUM 1024
#define CDIM 256
#define EPS_CAND 6.0f

// out region offsets in FP32 elements (zbar, zsoft, zhard, symbols, phisoft)
#define OFF_ZBAR   ((size_t)0)
#define OFF_ZSOFT  ((size_t)16777216)
#define OFF_ZHARD  ((size_t)33554432)
#define OFF_SYM    ((size_t)50331648)
#define OFF_PHI    ((size_t)50397184)

typedef __attribute__((ext_vector_type(8))) short bf16x8;
typedef __attribute__((ext_vector_type(4))) float f32x4;

__device__ __forceinline__ unsigned short f2bf(float f){
  unsigned u = __float_as_uint(f);
  u += 0x7fffu + ((u >> 16) & 1u);
  return (unsigned short)(u >> 16);
}
__device__ __forceinline__ float bf2f(unsigned short h){
  return __uint_as_float(((unsigned)h) << 16);
}
__device__ __forceinline__ float clamp01(float v){ return fminf(1.0f, fmaxf(0.0f, v)); }
__device__ __forceinline__ float clamp11(float v){ return fminf(1.0f, fmaxf(-1.0f, v)); }
__device__ __forceinline__ float dot4(float4 a, float4 b){ return a.x*b.x + a.y*b.y + a.z*b.z + a.w*b.w; }

// ---------- prep: centers fp32 -> bf16 row-major (cb16) + transposed (ct16) ----------
__global__ __launch_bounds__(256) void prep_convert(const float* __restrict__ centers,
                                                    unsigned short* __restrict__ cb16,
                                                    unsigned short* __restrict__ ct16){
  int gid = blockIdx.x*256 + threadIdx.x;
  int c = gid >> 6, d0 = (gid & 63)*4;
  float4 v = *reinterpret_cast<const float4*>(centers + (size_t)c*CDIM + d0);
  unsigned short b0=f2bf(v.x), b1=f2bf(v.y), b2=f2bf(v.z), b3=f2bf(v.w);
  unsigned lo = (unsigned)b0 | ((unsigned)b1<<16);
  unsigned hi = (unsigned)b2 | ((unsigned)b3<<16);
  *reinterpret_cast<uint2*>(cb16 + (size_t)c*CDIM + d0) = make_uint2(lo, hi);
  ct16[(size_t)(d0+0)*CNUM + c] = b0;
  ct16[(size_t)(d0+1)*CNUM + c] = b1;
  ct16[(size_t)(d0+2)*CNUM + c] = b2;
  ct16[(size_t)(d0+3)*CNUM + c] = b3;
}

__global__ __launch_bounds__(256) void prep_e2(const float* __restrict__ centers, float* __restrict__ e2){
  int k = blockIdx.x*256 + threadIdx.x;
  const float4* c4 = reinterpret_cast<const float4*>(centers) + (size_t)k*(CDIM/4);
  float s = 0.f;
  #pragma unroll
  for (int i=0;i<CDIM/4;i++){ float4 v = c4[i]; s += dot4(v,v); }
  e2[k] = s;
}

// ---------- K1: GEMM1 (MFMA bf16), writes s' = e2 - 2*x.e (fp32) into phisoft region ----------
// block = 64 tokens; grid 1024 XCD-swizzled. R7-proven.
__global__ __launch_bounds__(512) void k1_gemm1(const float* __restrict__ data,
                                                const unsigned short* __restrict__ cb16,
                                                const float* __restrict__ e2g,
                                                float* __restrict__ sqo){
  __shared__ unsigned short xb[64*256];
  __shared__ unsigned short cb[64*256];
  __shared__ float e2s[64];

  const int tid = threadIdx.x;
  const int w = tid>>6, lane = tid&63;
  const int l15 = lane&15, g = lane>>4;
  const int sb = (blockIdx.x & 7)*128 + (blockIdx.x >> 3);
  const int b = sb>>4, hw0 = (sb&15)*64;

  {
    const float* dp = data + ((size_t)b*CDIM + 32*w)*1024 + hw0 + lane;
    #pragma unroll
    for (int i=0;i<16;i++){
      int dd = 2*i;
      float v0 = dp[(size_t)dd*1024];
      float v1 = dp[(size_t)(dd+1)*1024];
      unsigned pk = (unsigned)f2bf(v0) | ((unsigned)f2bf(v1)<<16);
      int d = 32*w + dd;
      int s = d>>3;
      *reinterpret_cast<unsigned*>((char*)xb + lane*512 + (((s ^ (lane&7))<<4)) + (d&7)*2) = pk;
    }
  }

  const int tt  = w & 3;
  const int ch2 = w >> 2;

  for (int cc=0; cc<16; cc++){
    __syncthreads();
    #pragma unroll
    for (int it=0; it<4; it++){
      int e = tid + 512*it;
      int c = e>>5, s = e&31;
      uint4 v = *reinterpret_cast<const uint4*>(cb16 + ((size_t)(cc*64 + c))*CDIM + s*8);
      *reinterpret_cast<uint4*>((char*)cb + c*512 + ((s ^ (c&7))<<4)) = v;
    }
    if (tid < 64) e2s[tid] = e2g[cc*64 + tid];
    __syncthreads();

    f32x4 acc0 = {0.f,0.f,0.f,0.f}, acc1 = {0.f,0.f,0.f,0.f};
    const int t = 16*tt + l15;
    const int c0 = 32*ch2 + l15, c1 = c0 + 16;
    #pragma unroll
    for (int k=0;k<8;k++){
      bf16x8 bf = *reinterpret_cast<const bf16x8*>((const char*)xb + t*512 + (((4*k+g) ^ (t&7))<<4));
      bf16x8 a0 = *reinterpret_cast<const bf16x8*>((const char*)cb + c0*512 + (((4*k+g) ^ (c0&7))<<4));
      bf16x8 a1 = *reinterpret_cast<const bf16x8*>((const char*)cb + c1*512 + (((4*k+g) ^ (c1&7))<<4));
      acc0 = __builtin_amdgcn_mfma_f32_16x16x32_bf16(a0, bf, acc0, 0,0,0);
      acc1 = __builtin_amdgcn_mfma_f32_16x16x32_bf16(a1, bf, acc1, 0,0,0);
    }
    size_t outbase = (size_t)b*1048576 + (size_t)hw0 + 16*tt + l15;
    #pragma unroll
    for (int r=0;r<4;r++){
      int cr0 = 32*ch2 + 4*g + r;
      int cr1 = cr0 + 16;
      sqo[outbase + (size_t)(cc*64 + cr0)*1024] = e2s[cr0] - 2.0f*acc0[r];
      sqo[outbase + (size_t)(cc*64 + cr1)*1024] = e2s[cr1] - 2.0f*acc1[r];
    }
  }
}

// ---------- K2: softmax + exact argmin + phi/sym/zbar/zhard (R7 structure, bf16 LDS) ----------
// 16 tokens/block, grid 4096 XCD-swizzled. LDS 40 KB -> 4 blocks/CU.
__global__ __launch_bounds__(512, 8) void k2_soft(const float* __restrict__ data,
                                                  const float* __restrict__ centers,
                                                  float* __restrict__ out){
  __shared__ unsigned short S[16*1024];   // 32 KB: s' bf16 -> phi bf16; byte = t*2048 + (2c ^ ((t&7)<<4))
  __shared__ unsigned short H[16*256];    //  8 KB: hard bf16; byte = t*512 + (2d ^ ((t&7)<<4))

  const int tid = threadIdx.x;
  const int lane = tid&63;
  const int sb = (blockIdx.x & 7)*512 + (blockIdx.x >> 3);
  const int tok0 = sb*16;
  const int bb = tok0>>10, hw0 = tok0&1023;
  float* sqg = out + OFF_PHI;

  // ---- P0: read s' fp32 (in-place region), convert -> S bf16 ----
  #pragma unroll
  for (int it=0; it<8; it++){
    int e = tid + 512*it;              // 0..4095: c = e>>2, q = e&3
    int c = e>>2, q = e&3;
    float4 v = *reinterpret_cast<const float4*>(sqg + (size_t)bb*1048576 + (size_t)c*1024 + hw0 + 4*q);
    const float* vp = (const float*)&v;
    #pragma unroll
    for (int u=0;u<4;u++){
      int t = 4*q + u;
      *(unsigned short*)((char*)S + t*2048 + ((2*c) ^ ((t&7)<<4))) = f2bf(vp[u]);
    }
  }
  __syncthreads();

  // ---- P1: per-token softmax + fp64-refined argmin (R7 logic) ----
  {
    const int t = tid>>5;
    const int j = tid&31;
    const int hb = (lane>=32)?32:0;
    const char* srow = (const char*)S + t*2048;
    const int tswz = (t&7)<<4;

    float x2 = 0.f;
    const float* xp = data + (size_t)bb*262144 + hw0 + t;
    #pragma unroll
    for (int q2=0;q2<8;q2++){ float f = xp[(size_t)(j+32*q2)*1024]; x2 += f*f; }
    #pragma unroll
    for (int m=16;m>=1;m>>=1) x2 += __shfl_xor(x2, m);

    float a[32];
    float mns = 3.4e38f;
    #pragma unroll
    for (int i=0;i<32;i++){
      float sp = bf2f(*(const unsigned short*)(srow + ((2*(j+32*i)) ^ tswz)));
      a[i] = sp;
      mns = fminf(mns, sp);
    }
    #pragma unroll
    for (int m=16;m>=1;m>>=1) mns = fminf(mns, __shfl_xor(mns, m));
    float thr = mns + EPS_CAND;
    unsigned cm = 0;
    #pragma unroll
    for (int i=0;i<32;i++) if (a[i] < thr) cm |= (1u<<i);

    double bestd = 1.0e300; int bestk = CNUM;
    for(;;){
      unsigned long long bal = __ballot(cm != 0);
      unsigned half = (lane<32)? (unsigned)(bal & 0xffffffffULL) : (unsigned)(bal>>32);
      if (!half) break;
      int src = __ffs(half)-1;
      unsigned cmsrc = (unsigned)__shfl((int)cm, hb + src);
      int ii = __ffs(cmsrc)-1;
      int k = src + 32*ii;               // lane src owns centers {src, src+32, ...}
      if (j==src) cm &= ~(1u<<ii);
      double acc = 0.0;
      const float* crow = centers + (size_t)k*CDIM;
      #pragma unroll
      for (int q2=0;q2<8;q2++){
        double xv = (double)xp[(size_t)(j+32*q2)*1024];
        double ev = (double)crow[j+32*q2];
        double df = xv-ev; acc = fma(df,df,acc);
      }
      #pragma unroll
      for (int m=16;m>=1;m>>=1) acc += __shfl_xor(acc, m);
      if (acc < bestd || (acc==bestd && k<bestk)){ bestd=acc; bestk=k; }
    }
    if (j==0) out[OFF_SYM + tok0 + t] = (float)bestk;

    float dmn = sqrtf(fmaxf(mns + x2, 0.f));
    float sum = 0.f;
    #pragma unroll
    for (int i=0;i<32;i++){
      float d = sqrtf(fmaxf(a[i] + x2, 0.f));
      a[i] = __expf(dmn - d);
      sum += a[i];
    }
    #pragma unroll
    for (int m=16;m>=1;m>>=1) sum += __shfl_xor(sum, m);
    float rs = 1.f/sum;
    #pragma unroll
    for (int i=0;i<32;i++){
      *(unsigned short*)((char*)S + t*2048 + ((2*(j+32*i)) ^ tswz)) = f2bf(clamp01(a[i]*rs));
    }
    const float* hrow = centers + (size_t)bestk*CDIM;
    #pragma unroll
    for (int q2=0;q2<8;q2++){
      int c = j + 32*q2;
      *(unsigned short*)((char*)H + t*512 + ((2*c) ^ tswz)) = f2bf(hrow[c]);
    }
  }
  __syncthreads();

  // ---- P2a: phi fp32 store (same addresses as P0 read -> L2-hot overwrite) ----
  #pragma unroll
  for (int it=0; it<8; ++it){
    int e = tid + 512*it;
    int c = e>>2, q = e&3;
    float4 v; float* vp = (float*)&v;
    #pragma unroll
    for (int u=0;u<4;u++){
      int t = 4*q + u;
      vp[u] = bf2f(*(const unsigned short*)((const char*)S + t*2048 + ((2*c) ^ ((t&7)<<4))));
    }
    *reinterpret_cast<float4*>(sqg + (size_t)bb*1048576 + (size_t)c*1024 + hw0 + 4*q) = v;
  }
  // ---- P2b: zbar + zhard ----
  #pragma unroll
  for (int it=0; it<2; ++it){
    int e = tid + 512*it;
    int d = e>>2, q = e&3;
    float4 v; float* vp = (float*)&v;
    #pragma unroll
    for (int u=0;u<4;u++){
      int t = 4*q + u;
      vp[u] = bf2f(*(const unsigned short*)((const char*)H + t*512 + ((2*d) ^ ((t&7)<<4))));
    }
    size_t base = (size_t)bb*262144 + (size_t)d*1024 + hw0 + 4*q;
    *reinterpret_cast<float4*>(out + OFF_ZBAR  + base) = v;
    *reinterpret_cast<float4*>(out + OFF_ZHARD + base) = v;
  }
}

// ---------- K3: GEMM2 (MFMA bf16): zsoft^T = centersT . phi^T (R7-proven + swizzle) ----------
__global__ __launch_bounds__(512) void k3_gemm2(const float* __restrict__ phi,
                                                const unsigned short* __restrict__ ct16,
                                                float* __restrict__ zsoft){
  __shared__ unsigned short pls[64*64];
  const int tid = threadIdx.x;
  const int w = tid>>6, lane = tid&63;
  const int l15 = lane&15, g = lane>>4;
  const int sb = (blockIdx.x & 7)*128 + (blockIdx.x >> 3);
  const int b = sb>>4, hw0 = (sb&15)*64;

  f32x4 acc[2][4];
  #pragma unroll
  for (int h=0;h<2;h++)
    #pragma unroll
    for (int t2=0;t2<4;t2++) acc[h][t2] = (f32x4){0.f,0.f,0.f,0.f};

  for (int ks=0; ks<16; ks++){
    int k0s = ks*64;
    __syncthreads();
    #pragma unroll
    for (int it=0; it<4; it++){
      int e = tid + 512*it;
      int kp = e>>6, t = e&63;
      const float* pp = phi + (size_t)b*1048576 + (size_t)(k0s + 2*kp)*1024 + hw0 + t;
      float v0 = pp[0];
      float v1 = pp[1024];
      unsigned pk = (unsigned)f2bf(v0) | ((unsigned)f2bf(v1)<<16);
      int kk = 2*kp;
      int s = kk>>3;
      *reinterpret_cast<unsigned*>((char*)pls + t*128 + ((s ^ (t&7))<<4) + (kk&7)*2) = pk;
    }
    __syncthreads();
    #pragma unroll
    for (int ki=0; ki<2; ki++){
      int kk0 = k0s + 32*ki;
      bf16x8 a0 = *reinterpret_cast<const bf16x8*>(ct16 + (size_t)(32*w + l15)*CNUM + kk0 + 8*g);
      bf16x8 a1 = *reinterpret_cast<const bf16x8*>(ct16 + (size_t)(32*w + 16 + l15)*CNUM + kk0 + 8*g);
      #pragma unroll
      for (int t2=0;t2<4;t2++){
        int t = 16*t2 + l15;
        bf16x8 bf = *reinterpret_cast<const bf16x8*>((const char*)pls + t*128 + (((4*ki+g) ^ (t&7))<<4));
        acc[0][t2] = __builtin_amdgcn_mfma_f32_16x16x32_bf16(a0, bf, acc[0][t2], 0,0,0);
        acc[1][t2] = __builtin_amdgcn_mfma_f32_16x16x32_bf16(a1, bf, acc[1][t2], 0,0,0);
      }
    }
  }
  #pragma unroll
  for (int h=0;h<2;h++)
    #pragma unroll
    for (int t2=0;t2<4;t2++)
      #pragma unroll
      for (int r=0;r<4;r++){
        int d = 32*w + 16*h + 4*g + r;
        zsoft[(size_t)b*262144 + (size_t)d*1024 + hw0 + 16*t2 + l15] = clamp11(acc[h][t2][r]);
      }
}

extern "C" void kernel_launch(void* const* d_in, const int* in_sizes, int n_in,
                              void* d_out, int out_size, void* d_ws, size_t ws_size,
                              hipStream_t stream) {
  const float* data    = (const float*)d_in[0];
  const float* centers = (const float*)d_in[1];
  float* out           = (float*)d_out;

  unsigned short* cb16 = (unsigned short*)d_ws;                         // 512 KB
  unsigned short* ct16 = (unsigned short*)((char*)d_ws + 524288);       // 512 KB
  float*          e2   = (float*)((char*)d_ws + 1048576);               // 4 KB

  prep_convert<<<dim3(256), dim3(256), 0, stream>>>(centers, cb16, ct16);
  prep_e2<<<dim3(4), dim3(256), 0, stream>>>(centers, e2);
  k1_gemm1<<<dim3(1024), dim3(512), 0, stream>>>(data, cb16, e2, out + OFF_PHI);
  k2_soft<<<dim3(4096), dim3(512), 0, stream>>>(data, centers, out);
  k3_gemm2<<<dim3(1024), dim3(512), 0, stream>>>(out + OFF_PHI, ct16, out + OFF_ZSOFT);
}

// Round 14
// 541.956 us; speedup vs baseline: 1.9652x; 1.9652x over previous
//
#include <hip/hip_runtime.h>

#define CNUM 1024
#define CDIM 256
#define EPS_CAND 6.0f

// out region offsets in FP32 elements (zbar, zsoft, zhard, symbols, phisoft)
#define OFF_ZBAR   ((size_t)0)
#define OFF_ZSOFT  ((size_t)16777216)
#define OFF_ZHARD  ((size_t)33554432)
#define OFF_SYM    ((size_t)50331648)
#define OFF_PHI    ((size_t)50397184)

typedef __attribute__((ext_vector_type(8))) short bf16x8;
typedef __attribute__((ext_vector_type(4))) float f32x4;

__device__ __forceinline__ unsigned short f2bf(float f){
  unsigned u = __float_as_uint(f);
  u += 0x7fffu + ((u >> 16) & 1u);
  return (unsigned short)(u >> 16);
}
__device__ __forceinline__ float bf2f(unsigned short h){
  return __uint_as_float(((unsigned)h) << 16);
}
__device__ __forceinline__ float clamp01(float v){ return fminf(1.0f, fmaxf(0.0f, v)); }
__device__ __forceinline__ float clamp11(float v){ return fminf(1.0f, fmaxf(-1.0f, v)); }
__device__ __forceinline__ float dot4(float4 a, float4 b){ return a.x*b.x + a.y*b.y + a.z*b.z + a.w*b.w; }

// ---------- prep: centers fp32 -> bf16 row-major (cb16) + transposed (ct16) ----------
__global__ __launch_bounds__(256) void prep_convert(const float* __restrict__ centers,
                                                    unsigned short* __restrict__ cb16,
                                                    unsigned short* __restrict__ ct16){
  int gid = blockIdx.x*256 + threadIdx.x;
  int c = gid >> 6, d0 = (gid & 63)*4;
  float4 v = *reinterpret_cast<const float4*>(centers + (size_t)c*CDIM + d0);
  unsigned short b0=f2bf(v.x), b1=f2bf(v.y), b2=f2bf(v.z), b3=f2bf(v.w);
  unsigned lo = (unsigned)b0 | ((unsigned)b1<<16);
  unsigned hi = (unsigned)b2 | ((unsigned)b3<<16);
  *reinterpret_cast<uint2*>(cb16 + (size_t)c*CDIM + d0) = make_uint2(lo, hi);
  ct16[(size_t)(d0+0)*CNUM + c] = b0;
  ct16[(size_t)(d0+1)*CNUM + c] = b1;
  ct16[(size_t)(d0+2)*CNUM + c] = b2;
  ct16[(size_t)(d0+3)*CNUM + c] = b3;
}

__global__ __launch_bounds__(256) void prep_e2(const float* __restrict__ centers, float* __restrict__ e2){
  int k = blockIdx.x*256 + threadIdx.x;
  const float4* c4 = reinterpret_cast<const float4*>(centers) + (size_t)k*(CDIM/4);
  float s = 0.f;
  #pragma unroll
  for (int i=0;i<CDIM/4;i++){ float4 v = c4[i]; s += dot4(v,v); }
  e2[k] = s;
}

// ---------- K1: GEMM1 (MFMA bf16) + x2 -> full sq bf16 [c][65536 tokens] ----------
// block = 64 tokens; grid 1024 plain. Per c-row per block: 128B full-line write.
__global__ __launch_bounds__(512) void k1_gemm1(const float* __restrict__ data,
                                                const unsigned short* __restrict__ cb16,
                                                const float* __restrict__ e2g,
                                                unsigned short* __restrict__ scr16){
  __shared__ unsigned short xb[64*256];
  __shared__ unsigned short cb[64*256];
  __shared__ float e2s[64];
  __shared__ float px[512];
  __shared__ float x2s[64];

  const int tid = threadIdx.x;
  const int w = tid>>6, lane = tid&63;
  const int l15 = lane&15, g = lane>>4;
  const int b = blockIdx.x>>4, hw0 = (blockIdx.x&15)*64;

  // stage x (bf16, swizzled) + per-(wave,dim-range) x2 partials
  {
    float p2 = 0.f;
    const float* dp = data + ((size_t)b*CDIM + 32*w)*1024 + hw0 + lane;
    #pragma unroll
    for (int i=0;i<16;i++){
      int dd = 2*i;
      float v0 = dp[(size_t)dd*1024];
      float v1 = dp[(size_t)(dd+1)*1024];
      p2 += v0*v0 + v1*v1;
      unsigned pk = (unsigned)f2bf(v0) | ((unsigned)f2bf(v1)<<16);
      int d = 32*w + dd;
      int s = d>>3;
      *reinterpret_cast<unsigned*>((char*)xb + lane*512 + (((s ^ (lane&7))<<4)) + (d&7)*2) = pk;
    }
    px[w*64 + lane] = p2;
  }
  __syncthreads();
  if (tid < 64){
    float s = 0.f;
    #pragma unroll
    for (int wv=0; wv<8; wv++) s += px[wv*64 + tid];
    x2s[tid] = s;
  }

  const int tt  = w & 3;
  const int ch2 = w >> 2;
  const int t   = 16*tt + l15;
  const size_t tokglob = (size_t)b*1024 + hw0 + 16*tt + l15;

  for (int cc=0; cc<16; cc++){
    __syncthreads();
    #pragma unroll
    for (int it=0; it<4; it++){
      int e = tid + 512*it;
      int c = e>>5, s = e&31;
      uint4 v = *reinterpret_cast<const uint4*>(cb16 + ((size_t)(cc*64 + c))*CDIM + s*8);
      *reinterpret_cast<uint4*>((char*)cb + c*512 + ((s ^ (c&7))<<4)) = v;
    }
    if (tid < 64) e2s[tid] = e2g[cc*64 + tid];
    __syncthreads();

    f32x4 acc0 = {0.f,0.f,0.f,0.f}, acc1 = {0.f,0.f,0.f,0.f};
    const int c0 = 32*ch2 + l15, c1 = c0 + 16;
    #pragma unroll
    for (int k=0;k<8;k++){
      bf16x8 bf = *reinterpret_cast<const bf16x8*>((const char*)xb + t*512 + (((4*k+g) ^ (t&7))<<4));
      bf16x8 a0 = *reinterpret_cast<const bf16x8*>((const char*)cb + c0*512 + (((4*k+g) ^ (c0&7))<<4));
      bf16x8 a1 = *reinterpret_cast<const bf16x8*>((const char*)cb + c1*512 + (((4*k+g) ^ (c1&7))<<4));
      acc0 = __builtin_amdgcn_mfma_f32_16x16x32_bf16(a0, bf, acc0, 0,0,0);
      acc1 = __builtin_amdgcn_mfma_f32_16x16x32_bf16(a1, bf, acc1, 0,0,0);
    }
    float x2v = x2s[t];
    #pragma unroll
    for (int r=0;r<4;r++){
      int cr0 = 32*ch2 + 4*g + r;
      int cr1 = cr0 + 16;
      scr16[(size_t)(cc*64 + cr0)*65536 + tokglob] = f2bf(x2v - 2.0f*acc0[r] + e2s[cr0]);
      scr16[(size_t)(cc*64 + cr1)*65536 + tokglob] = f2bf(x2v - 2.0f*acc1[r] + e2s[cr1]);
    }
  }
}

// ---------- K2: softmax + exact argmin + phi/zbar/sym; 32 tokens/block, full-line stores ----------
__global__ __launch_bounds__(512, 4) void k2_soft(const float* __restrict__ data,
                                                  const float* __restrict__ centers,
                                                  const unsigned short* __restrict__ scr16,
                                                  float* __restrict__ out){
  __shared__ unsigned short S[32*1024];   // 64 KB: sq bf16 -> phi bf16; byte = t*2048 + (2c ^ ((t&7)<<4))
  __shared__ unsigned short H[32*256];    // 16 KB: hard bf16; byte = t*512 + (2d ^ ((t&7)<<4))

  const int tid = threadIdx.x;
  const int lane = tid&63;
  const int tok0 = blockIdx.x*32;
  const int bb = tok0>>10, hw0 = tok0&1023;

  // ---- P0: read sq bf16 [c][tok] -> S (transposed, swizzled) ----
  #pragma unroll
  for (int it=0; it<8; it++){
    int e = tid + 512*it;              // 0..4095: c = e>>2, chk = e&3 (8-token chunk)
    int c = e>>2, chk = e&3;
    uint4 v = *reinterpret_cast<const uint4*>(scr16 + (size_t)c*65536 + tok0 + 8*chk);
    const unsigned short* p = (const unsigned short*)&v;
    #pragma unroll
    for (int u=0;u<8;u++){
      int t = 8*chk + u;
      *(unsigned short*)((char*)S + t*2048 + ((2*c) ^ ((t&7)<<4))) = p[u];
    }
  }
  __syncthreads();

  // ---- P1: two passes of 16 tokens: softmax + fp64-refined argmin ----
  for (int p=0;p<2;p++){
    const int t = p*16 + (tid>>5);
    const int j = tid&31;
    const int hb = (lane>=32)?32:0;
    const int tswz = (t&7)<<4;
    char* srow = (char*)S + t*2048;

    float a[32];
    float mns = 3.4e38f;
    #pragma unroll
    for (int i=0;i<32;i++){
      float sp = bf2f(*(const unsigned short*)(srow + ((2*(j+32*i)) ^ tswz)));
      a[i] = sp;
      mns = fminf(mns, sp);
    }
    #pragma unroll
    for (int m=16;m>=1;m>>=1) mns = fminf(mns, __shfl_xor(mns, m));
    float thr = mns + EPS_CAND;
    unsigned cm = 0;
    #pragma unroll
    for (int i=0;i<32;i++) if (a[i] < thr) cm |= (1u<<i);

    double bestd = 1.0e300; int bestk = CNUM;
    const float* xp = data + (size_t)bb*262144 + hw0 + t;
    for(;;){
      unsigned long long bal = __ballot(cm != 0);
      unsigned half = (lane<32)? (unsigned)(bal & 0xffffffffULL) : (unsigned)(bal>>32);
      if (!half) break;
      int src = __ffs(half)-1;
      unsigned cmsrc = (unsigned)__shfl((int)cm, hb + src);
      int ii = __ffs(cmsrc)-1;
      int k = src + 32*ii;               // lane src owns centers {src+32*i}
      if (j==src) cm &= ~(1u<<ii);
      double acc = 0.0;
      const float* crow = centers + (size_t)k*CDIM;
      #pragma unroll
      for (int q2=0;q2<8;q2++){
        double xv = (double)xp[(size_t)(j+32*q2)*1024];
        double ev = (double)crow[j+32*q2];
        double df = xv-ev; acc = fma(df,df,acc);
      }
      #pragma unroll
      for (int m=16;m>=1;m>>=1) acc += __shfl_xor(acc, m);
      if (acc < bestd || (acc==bestd && k<bestk)){ bestd=acc; bestk=k; }
    }
    if (j==0) out[OFF_SYM + tok0 + t] = (float)bestk;

    float dmn = sqrtf(fmaxf(mns, 0.f));
    float sum = 0.f;
    #pragma unroll
    for (int i=0;i<32;i++){
      float d = sqrtf(fmaxf(a[i], 0.f));
      a[i] = __expf(dmn - d);
      sum += a[i];
    }
    #pragma unroll
    for (int m=16;m>=1;m>>=1) sum += __shfl_xor(sum, m);
    float rs = 1.f/sum;
    #pragma unroll
    for (int i=0;i<32;i++){
      *(unsigned short*)(srow + ((2*(j+32*i)) ^ tswz)) = f2bf(clamp01(a[i]*rs));
    }
    const float* hrow = centers + (size_t)bestk*CDIM;
    #pragma unroll
    for (int q2=0;q2<8;q2++){
      int c = j + 32*q2;
      *(unsigned short*)((char*)H + t*512 + ((2*c) ^ tswz)) = f2bf(hrow[c]);
    }
  }
  __syncthreads();

  // ---- P2a: phi fp32 stores (full 128B line per c-row) ----
  #pragma unroll
  for (int it=0; it<16; ++it){
    int e = tid + 512*it;              // 0..8191: c = e>>3, q = e&7
    int c = e>>3, q = e&7;
    float4 v; float* vp = (float*)&v;
    #pragma unroll
    for (int u=0;u<4;u++){
      int t = 4*q + u;
      vp[u] = bf2f(*(const unsigned short*)((const char*)S + t*2048 + ((2*c) ^ ((t&7)<<4))));
    }
    *reinterpret_cast<float4*>(out + OFF_PHI + (size_t)bb*1048576 + (size_t)c*1024 + hw0 + 4*q) = v;
  }
  // ---- P2b: zbar stores (full 128B line per d-row); zhard comes from d2d copy ----
  #pragma unroll
  for (int it=0; it<4; ++it){
    int e = tid + 512*it;              // 0..2047: d = e>>3, q = e&7
    int d = e>>3, q = e&7;
    float4 v; float* vp = (float*)&v;
    #pragma unroll
    for (int u=0;u<4;u++){
      int t = 4*q + u;
      vp[u] = bf2f(*(const unsigned short*)((const char*)H + t*512 + ((2*d) ^ ((t&7)<<4))));
    }
    *reinterpret_cast<float4*>(out + OFF_ZBAR + (size_t)bb*262144 + (size_t)d*1024 + hw0 + 4*q) = v;
  }
}

// ---------- K3: GEMM2 (MFMA bf16): zsoft^T = centersT . phi^T (R7-proven) ----------
__global__ __launch_bounds__(512) void k3_gemm2(const float* __restrict__ phi,
                                                const unsigned short* __restrict__ ct16,
                                                float* __restrict__ zsoft){
  __shared__ unsigned short pls[64*64];
  const int tid = threadIdx.x;
  const int w = tid>>6, lane = tid&63;
  const int l15 = lane&15, g = lane>>4;
  const int b = blockIdx.x>>4, hw0 = (blockIdx.x&15)*64;

  f32x4 acc[2][4];
  #pragma unroll
  for (int h=0;h<2;h++)
    #pragma unroll
    for (int t2=0;t2<4;t2++) acc[h][t2] = (f32x4){0.f,0.f,0.f,0.f};

  for (int ks=0; ks<16; ks++){
    int k0s = ks*64;
    __syncthreads();
    #pragma unroll
    for (int it=0; it<4; it++){
      int e = tid + 512*it;
      int kp = e>>6, t = e&63;
      const float* pp = phi + (size_t)b*1048576 + (size_t)(k0s + 2*kp)*1024 + hw0 + t;
      float v0 = pp[0];
      float v1 = pp[1024];
      unsigned pk = (unsigned)f2bf(v0) | ((unsigned)f2bf(v1)<<16);
      int kk = 2*kp;
      int s = kk>>3;
      *reinterpret_cast<unsigned*>((char*)pls + t*128 + ((s ^ (t&7))<<4) + (kk&7)*2) = pk;
    }
    __syncthreads();
    #pragma unroll
    for (int ki=0; ki<2; ki++){
      int kk0 = k0s + 32*ki;
      bf16x8 a0 = *reinterpret_cast<const bf16x8*>(ct16 + (size_t)(32*w + l15)*CNUM + kk0 + 8*g);
      bf16x8 a1 = *reinterpret_cast<const bf16x8*>(ct16 + (size_t)(32*w + 16 + l15)*CNUM + kk0 + 8*g);
      #pragma unroll
      for (int t2=0;t2<4;t2++){
        int t = 16*t2 + l15;
        bf16x8 bf = *reinterpret_cast<const bf16x8*>((const char*)pls + t*128 + (((4*ki+g) ^ (t&7))<<4));
        acc[0][t2] = __builtin_amdgcn_mfma_f32_16x16x32_bf16(a0, bf, acc[0][t2], 0,0,0);
        acc[1][t2] = __builtin_amdgcn_mfma_f32_16x16x32_bf16(a1, bf, acc[1][t2], 0,0,0);
      }
    }
  }
  #pragma unroll
  for (int h=0;h<2;h++)
    #pragma unroll
    for (int t2=0;t2<4;t2++)
      #pragma unroll
      for (int r=0;r<4;r++){
        int d = 32*w + 16*h + 4*g + r;
        zsoft[(size_t)b*262144 + (size_t)d*1024 + hw0 + 16*t2 + l15] = clamp11(acc[h][t2][r]);
      }
}

extern "C" void kernel_launch(void* const* d_in, const int* in_sizes, int n_in,
                              void* d_out, int out_size, void* d_ws, size_t ws_size,
                              hipStream_t stream) {
  const float* data    = (const float*)d_in[0];
  const float* centers = (const float*)d_in[1];
  float* out           = (float*)d_out;

  unsigned short* cb16 = (unsigned short*)d_ws;                         // 512 KB
  unsigned short* ct16 = (unsigned short*)((char*)d_ws + 524288);       // 512 KB
  float*          e2   = (float*)((char*)d_ws + 1048576);               // 4 KB
  // sq bf16 scratch (134 MB) lives in the zsoft+zhard regions, consumed before they're written
  unsigned short* scr16 = (unsigned short*)(out + OFF_ZSOFT);

  prep_convert<<<dim3(256), dim3(256), 0, stream>>>(centers, cb16, ct16);
  prep_e2<<<dim3(4), dim3(256), 0, stream>>>(centers, e2);
  k1_gemm1<<<dim3(1024), dim3(512), 0, stream>>>(data, cb16, e2, scr16);
  k2_soft<<<dim3(2048), dim3(512), 0, stream>>>(data, centers, scr16, out);
  // zhard = zbar (forward values identical); d2d copy after k2 consumed the zhard-region scratch
  hipMemcpyAsync(out + OFF_ZHARD, out + OFF_ZBAR, (size_t)16777216*4, hipMemcpyDeviceToDevice, stream);
  k3_gemm2<<<dim3(1024), dim3(512), 0, stream>>>(out + OFF_PHI, ct16, out + OFF_ZSOFT);
}

// Round 15
// 508.395 us; speedup vs baseline: 2.0950x; 1.0660x over previous
//
#include <hip/hip_runtime.h>

#define CNUM 1024
#define CDIM 256
#define EPS_CAND 6.0f

// out region offsets in FP32 elements (zbar, zsoft, zhard, symbols, phisoft)
#define OFF_ZBAR   ((size_t)0)
#define OFF_ZSOFT  ((size_t)16777216)
#define OFF_ZHARD  ((size_t)33554432)
#define OFF_SYM    ((size_t)50331648)
#define OFF_PHI    ((size_t)50397184)

typedef __attribute__((ext_vector_type(8))) short bf16x8;
typedef __attribute__((ext_vector_type(4))) float f32x4;

__device__ __forceinline__ unsigned short f2bf(float f){
  unsigned u = __float_as_uint(f);
  u += 0x7fffu + ((u >> 16) & 1u);
  return (unsigned short)(u >> 16);
}
__device__ __forceinline__ float bf2f(unsigned short h){
  return __uint_as_float(((unsigned)h) << 16);
}
__device__ __forceinline__ float clamp01(float v){ return fminf(1.0f, fmaxf(0.0f, v)); }
__device__ __forceinline__ float clamp11(float v){ return fminf(1.0f, fmaxf(-1.0f, v)); }
__device__ __forceinline__ float dot4(float4 a, float4 b){ return a.x*b.x + a.y*b.y + a.z*b.z + a.w*b.w; }

// ---------- prep ----------
__global__ __launch_bounds__(256) void prep_convert(const float* __restrict__ centers,
                                                    unsigned short* __restrict__ cb16,
                                                    unsigned short* __restrict__ ct16){
  int gid = blockIdx.x*256 + threadIdx.x;
  int c = gid >> 6, d0 = (gid & 63)*4;
  float4 v = *reinterpret_cast<const float4*>(centers + (size_t)c*CDIM + d0);
  unsigned short b0=f2bf(v.x), b1=f2bf(v.y), b2=f2bf(v.z), b3=f2bf(v.w);
  unsigned lo = (unsigned)b0 | ((unsigned)b1<<16);
  unsigned hi = (unsigned)b2 | ((unsigned)b3<<16);
  *reinterpret_cast<uint2*>(cb16 + (size_t)c*CDIM + d0) = make_uint2(lo, hi);
  ct16[(size_t)(d0+0)*CNUM + c] = b0;
  ct16[(size_t)(d0+1)*CNUM + c] = b1;
  ct16[(size_t)(d0+2)*CNUM + c] = b2;
  ct16[(size_t)(d0+3)*CNUM + c] = b3;
}

__global__ __launch_bounds__(256) void prep_e2(const float* __restrict__ centers, float* __restrict__ e2){
  int k = blockIdx.x*256 + threadIdx.x;
  const float4* c4 = reinterpret_cast<const float4*>(centers) + (size_t)k*(CDIM/4);
  float s = 0.f;
  #pragma unroll
  for (int i=0;i<CDIM/4;i++){ float4 v = c4[i]; s += dot4(v,v); }
  e2[k] = s;
}

// ---------- K1: GEMM1 (MFMA bf16) + x2 -> full sq bf16 [c][65536 tokens] ----------
__global__ __launch_bounds__(512) void k1_gemm1(const float* __restrict__ data,
                                                const unsigned short* __restrict__ cb16,
                                                const float* __restrict__ e2g,
                                                unsigned short* __restrict__ scr16){
  __shared__ unsigned short xb[64*256];
  __shared__ unsigned short cb[64*256];
  __shared__ float e2s[64];
  __shared__ float px[512];
  __shared__ float x2s[64];

  const int tid = threadIdx.x;
  const int w = tid>>6, lane = tid&63;
  const int l15 = lane&15, g = lane>>4;
  const int b = blockIdx.x>>4, hw0 = (blockIdx.x&15)*64;

  {
    float p2 = 0.f;
    const float* dp = data + ((size_t)b*CDIM + 32*w)*1024 + hw0 + lane;
    #pragma unroll
    for (int i=0;i<16;i++){
      int dd = 2*i;
      float v0 = dp[(size_t)dd*1024];
      float v1 = dp[(size_t)(dd+1)*1024];
      p2 += v0*v0 + v1*v1;
      unsigned pk = (unsigned)f2bf(v0) | ((unsigned)f2bf(v1)<<16);
      int d = 32*w + dd;
      int s = d>>3;
      *reinterpret_cast<unsigned*>((char*)xb + lane*512 + (((s ^ (lane&7))<<4)) + (d&7)*2) = pk;
    }
    px[w*64 + lane] = p2;
  }
  __syncthreads();
  if (tid < 64){
    float s = 0.f;
    #pragma unroll
    for (int wv=0; wv<8; wv++) s += px[wv*64 + tid];
    x2s[tid] = s;
  }

  const int tt  = w & 3;
  const int ch2 = w >> 2;
  const int t   = 16*tt + l15;
  const size_t tokglob = (size_t)b*1024 + hw0 + 16*tt + l15;

  for (int cc=0; cc<16; cc++){
    __syncthreads();
    #pragma unroll
    for (int it=0; it<4; it++){
      int e = tid + 512*it;
      int c = e>>5, s = e&31;
      uint4 v = *reinterpret_cast<const uint4*>(cb16 + ((size_t)(cc*64 + c))*CDIM + s*8);
      *reinterpret_cast<uint4*>((char*)cb + c*512 + ((s ^ (c&7))<<4)) = v;
    }
    if (tid < 64) e2s[tid] = e2g[cc*64 + tid];
    __syncthreads();

    f32x4 acc0 = {0.f,0.f,0.f,0.f}, acc1 = {0.f,0.f,0.f,0.f};
    const int c0 = 32*ch2 + l15, c1 = c0 + 16;
    #pragma unroll
    for (int k=0;k<8;k++){
      bf16x8 bf = *reinterpret_cast<const bf16x8*>((const char*)xb + t*512 + (((4*k+g) ^ (t&7))<<4));
      bf16x8 a0 = *reinterpret_cast<const bf16x8*>((const char*)cb + c0*512 + (((4*k+g) ^ (c0&7))<<4));
      bf16x8 a1 = *reinterpret_cast<const bf16x8*>((const char*)cb + c1*512 + (((4*k+g) ^ (c1&7))<<4));
      acc0 = __builtin_amdgcn_mfma_f32_16x16x32_bf16(a0, bf, acc0, 0,0,0);
      acc1 = __builtin_amdgcn_mfma_f32_16x16x32_bf16(a1, bf, acc1, 0,0,0);
    }
    float x2v = x2s[t];
    #pragma unroll
    for (int r=0;r<4;r++){
      int cr0 = 32*ch2 + 4*g + r;
      int cr1 = cr0 + 16;
      scr16[(size_t)(cc*64 + cr0)*65536 + tokglob] = f2bf(x2v - 2.0f*acc0[r] + e2s[cr0]);
      scr16[(size_t)(cc*64 + cr1)*65536 + tokglob] = f2bf(x2v - 2.0f*acc1[r] + e2s[cr1]);
    }
  }
}

// ---------- K2: softmax + exact argmin + outputs. FUSE_G2: + zhard + in-block GEMM2 ----------
// 32 tokens/block, grid 2048, LDS 80 KB -> 2 blocks/CU. All global stores = full 128B lines.
template<bool FUSE_G2>
__global__ __launch_bounds__(512, 4) void k2_soft(const float* __restrict__ data,
                                                  const float* __restrict__ centers,
                                                  const unsigned short* __restrict__ ct16,
                                                  const unsigned short* __restrict__ scr16,
                                                  float* __restrict__ out){
  __shared__ unsigned short S[32*1024];   // 64 KB: sq bf16 -> phi bf16; byte = t*2048 + (2c ^ ((t&7)<<4))
  __shared__ unsigned short H[32*256];    // 16 KB: hard bf16 (-> zsoft bf16); byte = t*512 + (2d ^ ((t&7)<<4))

  const int tid = threadIdx.x;
  const int w = tid>>6, lane = tid&63;
  const int l15 = lane&15, g = lane>>4;
  const int tok0 = blockIdx.x*32;
  const int bb = tok0>>10, hw0 = tok0&1023;

  // ---- P0: read sq bf16 [c][tok] -> S (transposed, swizzled) ----
  #pragma unroll
  for (int it=0; it<8; it++){
    int e = tid + 512*it;              // 0..4095: c = e>>2, chk = e&3
    int c = e>>2, chk = e&3;
    uint4 v = *reinterpret_cast<const uint4*>(scr16 + (size_t)c*65536 + tok0 + 8*chk);
    const unsigned short* p = (const unsigned short*)&v;
    #pragma unroll
    for (int u=0;u<8;u++){
      int t = 8*chk + u;
      *(unsigned short*)((char*)S + t*2048 + ((2*c) ^ ((t&7)<<4))) = p[u];
    }
  }
  __syncthreads();

  // ---- P1: two passes of 16 tokens: softmax + fp64-refined argmin ----
  for (int p=0;p<2;p++){
    const int t = p*16 + (tid>>5);
    const int j = tid&31;
    const int hb = (lane>=32)?32:0;
    const int tswz = (t&7)<<4;
    char* srow = (char*)S + t*2048;

    float a[32];
    float mns = 3.4e38f;
    #pragma unroll
    for (int i=0;i<32;i++){
      float sp = bf2f(*(const unsigned short*)(srow + ((2*(j+32*i)) ^ tswz)));
      a[i] = sp;
      mns = fminf(mns, sp);
    }
    #pragma unroll
    for (int m=16;m>=1;m>>=1) mns = fminf(mns, __shfl_xor(mns, m));
    float thr = mns + EPS_CAND;
    unsigned cm = 0;
    #pragma unroll
    for (int i=0;i<32;i++) if (a[i] < thr) cm |= (1u<<i);

    double bestd = 1.0e300; int bestk = CNUM;
    const float* xp = data + (size_t)bb*262144 + hw0 + t;
    for(;;){
      unsigned long long bal = __ballot(cm != 0);
      unsigned half = (lane<32)? (unsigned)(bal & 0xffffffffULL) : (unsigned)(bal>>32);
      if (!half) break;
      int src = __ffs(half)-1;
      unsigned cmsrc = (unsigned)__shfl((int)cm, hb + src);
      int ii = __ffs(cmsrc)-1;
      int k = src + 32*ii;
      if (j==src) cm &= ~(1u<<ii);
      double acc = 0.0;
      const float* crow = centers + (size_t)k*CDIM;
      #pragma unroll
      for (int q2=0;q2<8;q2++){
        double xv = (double)xp[(size_t)(j+32*q2)*1024];
        double ev = (double)crow[j+32*q2];
        double df = xv-ev; acc = fma(df,df,acc);
      }
      #pragma unroll
      for (int m=16;m>=1;m>>=1) acc += __shfl_xor(acc, m);
      if (acc < bestd || (acc==bestd && k<bestk)){ bestd=acc; bestk=k; }
    }
    if (j==0) out[OFF_SYM + tok0 + t] = (float)bestk;

    float dmn = sqrtf(fmaxf(mns, 0.f));
    float sum = 0.f;
    #pragma unroll
    for (int i=0;i<32;i++){
      float d = sqrtf(fmaxf(a[i], 0.f));
      a[i] = __expf(dmn - d);
      sum += a[i];
    }
    #pragma unroll
    for (int m=16;m>=1;m>>=1) sum += __shfl_xor(sum, m);
    float rs = 1.f/sum;
    #pragma unroll
    for (int i=0;i<32;i++){
      *(unsigned short*)(srow + ((2*(j+32*i)) ^ tswz)) = f2bf(clamp01(a[i]*rs));
    }
    const float* hrow = centers + (size_t)bestk*CDIM;
    #pragma unroll
    for (int q2=0;q2<8;q2++){
      int c = j + 32*q2;
      *(unsigned short*)((char*)H + t*512 + ((2*c) ^ tswz)) = f2bf(hrow[c]);
    }
  }
  __syncthreads();

  // ---- P2a: phi fp32 stores (full 128B line) ----
  #pragma unroll
  for (int it=0; it<16; ++it){
    int e = tid + 512*it;              // c = e>>3, q = e&7
    int c = e>>3, q = e&7;
    float4 v; float* vp = (float*)&v;
    #pragma unroll
    for (int u=0;u<4;u++){
      int t = 4*q + u;
      vp[u] = bf2f(*(const unsigned short*)((const char*)S + t*2048 + ((2*c) ^ ((t&7)<<4))));
    }
    *reinterpret_cast<float4*>(out + OFF_PHI + (size_t)bb*1048576 + (size_t)c*1024 + hw0 + 4*q) = v;
  }
  // ---- P2b: zbar (+zhard when fused) stores (full 128B line) ----
  #pragma unroll
  for (int it=0; it<4; ++it){
    int e = tid + 512*it;              // d = e>>3, q = e&7
    int d = e>>3, q = e&7;
    float4 v; float* vp = (float*)&v;
    #pragma unroll
    for (int u=0;u<4;u++){
      int t = 4*q + u;
      vp[u] = bf2f(*(const unsigned short*)((const char*)H + t*512 + ((2*d) ^ ((t&7)<<4))));
    }
    size_t base = (size_t)bb*262144 + (size_t)d*1024 + hw0 + 4*q;
    *reinterpret_cast<float4*>(out + OFF_ZBAR + base) = v;
    if (FUSE_G2) *reinterpret_cast<float4*>(out + OFF_ZHARD + base) = v;
  }

  if (FUSE_G2){
    __syncthreads();   // H consumed; S (phi bf16) still intact
    // ---- P3: GEMM2 (R8-P6-proven fragments): zsoft^T = ct16 . phi^T ----
    f32x4 z00={0.f,0.f,0.f,0.f}, z01=z00, z10=z00, z11=z00;
    const unsigned short* ar0 = ct16 + (size_t)(16*w + l15)*CNUM;
    const unsigned short* ar1 = ct16 + (size_t)(16*(w+8) + l15)*CNUM;
    const char* br0 = (const char*)S + (size_t)l15*2048;
    const char* br1 = (const char*)S + (size_t)(16+l15)*2048;
    const int bswz = (l15&7)<<4;       // (16+l15)&7 == l15&7
    #pragma unroll 8
    for (int s=0;s<32;s++){
      bf16x8 b0 = *reinterpret_cast<const bf16x8*>(br0 + ((64*s + 16*g) ^ bswz));
      bf16x8 b1 = *reinterpret_cast<const bf16x8*>(br1 + ((64*s + 16*g) ^ bswz));
      bf16x8 a0 = *reinterpret_cast<const bf16x8*>(ar0 + 32*s + 8*g);
      bf16x8 a1 = *reinterpret_cast<const bf16x8*>(ar1 + 32*s + 8*g);
      z00 = __builtin_amdgcn_mfma_f32_16x16x32_bf16(a0, b0, z00, 0,0,0);
      z01 = __builtin_amdgcn_mfma_f32_16x16x32_bf16(a0, b1, z01, 0,0,0);
      z10 = __builtin_amdgcn_mfma_f32_16x16x32_bf16(a1, b0, z10, 0,0,0);
      z11 = __builtin_amdgcn_mfma_f32_16x16x32_bf16(a1, b1, z11, 0,0,0);
    }
    // stage zsoft bf16 -> H: t = nt*16+l15, d = 16*(w+8mi)+4g+r
    #pragma unroll
    for (int mi=0;mi<2;mi++){
      #pragma unroll
      for (int nt=0;nt<2;nt++){
        f32x4 ac = (mi==0) ? (nt==0 ? z00 : z01) : (nt==0 ? z10 : z11);
        int mt = w + 8*mi;
        int t  = nt*16 + l15;
        int d0 = 16*mt + 4*g;
        unsigned short h0,h1;
        unsigned w0,w1;
        h0 = f2bf(clamp11(ac[0])); h1 = f2bf(clamp11(ac[1])); w0 = (unsigned)h0 | ((unsigned)h1<<16);
        h0 = f2bf(clamp11(ac[2])); h1 = f2bf(clamp11(ac[3])); w1 = (unsigned)h0 | ((unsigned)h1<<16);
        *reinterpret_cast<uint2*>((char*)H + t*512 + ((2*d0) ^ ((t&7)<<4))) = make_uint2(w0,w1);
      }
    }
    __syncthreads();
    // ---- P4: zsoft stores (full 128B line) ----
    #pragma unroll
    for (int it=0; it<4; ++it){
      int e = tid + 512*it;
      int d = e>>3, q = e&7;
      float4 v; float* vp = (float*)&v;
      #pragma unroll
      for (int u=0;u<4;u++){
        int t = 4*q + u;
        vp[u] = bf2f(*(const unsigned short*)((const char*)H + t*512 + ((2*d) ^ ((t&7)<<4))));
      }
      *reinterpret_cast<float4*>(out + OFF_ZSOFT + (size_t)bb*262144 + (size_t)d*1024 + hw0 + 4*q) = v;
    }
  }
}

// ---------- K3 (fallback only): GEMM2 from phi fp32 (R7-proven) ----------
__global__ __launch_bounds__(512) void k3_gemm2(const float* __restrict__ phi,
                                                const unsigned short* __restrict__ ct16,
                                                float* __restrict__ zsoft){
  __shared__ unsigned short pls[64*64];
  const int tid = threadIdx.x;
  const int w = tid>>6, lane = tid&63;
  const int l15 = lane&15, g = lane>>4;
  const int b = blockIdx.x>>4, hw0 = (blockIdx.x&15)*64;

  f32x4 acc[2][4];
  #pragma unroll
  for (int h=0;h<2;h++)
    #pragma unroll
    for (int t2=0;t2<4;t2++) acc[h][t2] = (f32x4){0.f,0.f,0.f,0.f};

  for (int ks=0; ks<16; ks++){
    int k0s = ks*64;
    __syncthreads();
    #pragma unroll
    for (int it=0; it<4; it++){
      int e = tid + 512*it;
      int kp = e>>6, t = e&63;
      const float* pp = phi + (size_t)b*1048576 + (size_t)(k0s + 2*kp)*1024 + hw0 + t;
      float v0 = pp[0];
      float v1 = pp[1024];
      unsigned pk = (unsigned)f2bf(v0) | ((unsigned)f2bf(v1)<<16);
      int kk = 2*kp;
      int s = kk>>3;
      *reinterpret_cast<unsigned*>((char*)pls + t*128 + ((s ^ (t&7))<<4) + (kk&7)*2) = pk;
    }
    __syncthreads();
    #pragma unroll
    for (int ki=0; ki<2; ki++){
      int kk0 = k0s + 32*ki;
      bf16x8 a0 = *reinterpret_cast<const bf16x8*>(ct16 + (size_t)(32*w + l15)*CNUM + kk0 + 8*g);
      bf16x8 a1 = *reinterpret_cast<const bf16x8*>(ct16 + (size_t)(32*w + 16 + l15)*CNUM + kk0 + 8*g);
      #pragma unroll
      for (int t2=0;t2<4;t2++){
        int t = 16*t2 + l15;
        bf16x8 bf = *reinterpret_cast<const bf16x8*>((const char*)pls + t*128 + (((4*ki+g) ^ (t&7))<<4));
        acc[0][t2] = __builtin_amdgcn_mfma_f32_16x16x32_bf16(a0, bf, acc[0][t2], 0,0,0);
        acc[1][t2] = __builtin_amdgcn_mfma_f32_16x16x32_bf16(a1, bf, acc[1][t2], 0,0,0);
      }
    }
  }
  #pragma unroll
  for (int h=0;h<2;h++)
    #pragma unroll
    for (int t2=0;t2<4;t2++)
      #pragma unroll
      for (int r=0;r<4;r++){
        int d = 32*w + 16*h + 4*g + r;
        zsoft[(size_t)b*262144 + (size_t)d*1024 + hw0 + 16*t2 + l15] = clamp11(acc[h][t2][r]);
      }
}

extern "C" void kernel_launch(void* const* d_in, const int* in_sizes, int n_in,
                              void* d_out, int out_size, void* d_ws, size_t ws_size,
                              hipStream_t stream) {
  const float* data    = (const float*)d_in[0];
  const float* centers = (const float*)d_in[1];
  float* out           = (float*)d_out;

  const size_t SQ_BYTES = (size_t)1024*65536*2;   // 134,217,728
  const bool wsmode = (ws_size >= SQ_BYTES + 524288 + 524288 + 4096);

  unsigned short *scr16, *cb16, *ct16;
  float *e2;
  if (wsmode){
    scr16 = (unsigned short*)d_ws;
    cb16  = (unsigned short*)((char*)d_ws + SQ_BYTES);
    ct16  = (unsigned short*)((char*)d_ws + SQ_BYTES + 524288);
    e2    = (float*)((char*)d_ws + SQ_BYTES + 1048576);
  } else {
    scr16 = (unsigned short*)(out + OFF_ZSOFT);   // zsoft+zhard as scratch (R14-proven)
    cb16  = (unsigned short*)d_ws;
    ct16  = (unsigned short*)((char*)d_ws + 524288);
    e2    = (float*)((char*)d_ws + 1048576);
  }

  prep_convert<<<dim3(256), dim3(256), 0, stream>>>(centers, cb16, ct16);
  prep_e2<<<dim3(4), dim3(256), 0, stream>>>(centers, e2);
  k1_gemm1<<<dim3(1024), dim3(512), 0, stream>>>(data, cb16, e2, scr16);
  if (wsmode){
    // fused: k2 writes phi/sym/zbar/zhard/zsoft; no copy, no k3
    k2_soft<true><<<dim3(2048), dim3(512), 0, stream>>>(data, centers, ct16, scr16, out);
  } else {
    // R14-proven path
    k2_soft<false><<<dim3(2048), dim3(512), 0, stream>>>(data, centers, ct16, scr16, out);
    hipMemcpyAsync(out + OFF_ZHARD, out + OFF_ZBAR, (size_t)16777216*4, hipMemcpyDeviceToDevice, stream);
    k3_gemm2<<<dim3(1024), dim3(512), 0, stream>>>(out + OFF_PHI, ct16, out + OFF_ZSOFT);
  }
}

// Round 16
// 497.952 us; speedup vs baseline: 2.1389x; 1.0210x over previous
//
#include <hip/hip_runtime.h>

#define CNUM 1024
#define CDIM 256
#define EPS_CAND 6.0f

// out region offsets in FP32 elements (zbar, zsoft, zhard, symbols, phisoft)
#define OFF_ZBAR   ((size_t)0)
#define OFF_ZSOFT  ((size_t)16777216)
#define OFF_ZHARD  ((size_t)33554432)
#define OFF_SYM    ((size_t)50331648)
#define OFF_PHI    ((size_t)50397184)

typedef __attribute__((ext_vector_type(8))) short bf16x8;
typedef __attribute__((ext_vector_type(4))) float f32x4;

__device__ __forceinline__ unsigned short f2bf(float f){
  unsigned u = __float_as_uint(f);
  u += 0x7fffu + ((u >> 16) & 1u);
  return (unsigned short)(u >> 16);
}
__device__ __forceinline__ float bf2f(unsigned short h){
  return __uint_as_float(((unsigned)h) << 16);
}
__device__ __forceinline__ float clamp01(float v){ return fminf(1.0f, fmaxf(0.0f, v)); }
__device__ __forceinline__ float clamp11(float v){ return fminf(1.0f, fmaxf(-1.0f, v)); }
__device__ __forceinline__ float dot4(float4 a, float4 b){ return a.x*b.x + a.y*b.y + a.z*b.z + a.w*b.w; }

// ---------- prep ----------
__global__ __launch_bounds__(256) void prep_convert(const float* __restrict__ centers,
                                                    unsigned short* __restrict__ cb16,
                                                    unsigned short* __restrict__ ct16){
  int gid = blockIdx.x*256 + threadIdx.x;
  int c = gid >> 6, d0 = (gid & 63)*4;
  float4 v = *reinterpret_cast<const float4*>(centers + (size_t)c*CDIM + d0);
  unsigned short b0=f2bf(v.x), b1=f2bf(v.y), b2=f2bf(v.z), b3=f2bf(v.w);
  unsigned lo = (unsigned)b0 | ((unsigned)b1<<16);
  unsigned hi = (unsigned)b2 | ((unsigned)b3<<16);
  *reinterpret_cast<uint2*>(cb16 + (size_t)c*CDIM + d0) = make_uint2(lo, hi);
  ct16[(size_t)(d0+0)*CNUM + c] = b0;
  ct16[(size_t)(d0+1)*CNUM + c] = b1;
  ct16[(size_t)(d0+2)*CNUM + c] = b2;
  ct16[(size_t)(d0+3)*CNUM + c] = b3;
}

__global__ __launch_bounds__(256) void prep_e2(const float* __restrict__ centers, float* __restrict__ e2){
  int k = blockIdx.x*256 + threadIdx.x;
  const float4* c4 = reinterpret_cast<const float4*>(centers) + (size_t)k*(CDIM/4);
  float s = 0.f;
  #pragma unroll
  for (int i=0;i<CDIM/4;i++){ float4 v = c4[i]; s += dot4(v,v); }
  e2[k] = s;
}

// ---------- K1: GEMM1 (MFMA bf16) + x2 -> sq bf16 BLOCKED [tokblk32][1024 c][32 tok] ----------
__global__ __launch_bounds__(512) void k1_gemm1(const float* __restrict__ data,
                                                const unsigned short* __restrict__ cb16,
                                                const float* __restrict__ e2g,
                                                unsigned short* __restrict__ scr16){
  __shared__ unsigned short xb[64*256];
  __shared__ unsigned short cb[64*256];
  __shared__ float e2s[64];
  __shared__ float px[512];
  __shared__ float x2s[64];

  const int tid = threadIdx.x;
  const int w = tid>>6, lane = tid&63;
  const int l15 = lane&15, g = lane>>4;
  const int b = blockIdx.x>>4, hw0 = (blockIdx.x&15)*64;

  {
    float p2 = 0.f;
    const float* dp = data + ((size_t)b*CDIM + 32*w)*1024 + hw0 + lane;
    #pragma unroll
    for (int i=0;i<16;i++){
      int dd = 2*i;
      float v0 = dp[(size_t)dd*1024];
      float v1 = dp[(size_t)(dd+1)*1024];
      p2 += v0*v0 + v1*v1;
      unsigned pk = (unsigned)f2bf(v0) | ((unsigned)f2bf(v1)<<16);
      int d = 32*w + dd;
      int s = d>>3;
      *reinterpret_cast<unsigned*>((char*)xb + lane*512 + (((s ^ (lane&7))<<4)) + (d&7)*2) = pk;
    }
    px[w*64 + lane] = p2;
  }
  __syncthreads();
  if (tid < 64){
    float s = 0.f;
    #pragma unroll
    for (int wv=0; wv<8; wv++) s += px[wv*64 + tid];
    x2s[tid] = s;
  }

  const int tt  = w & 3;
  const int ch2 = w >> 2;
  const int t   = 16*tt + l15;
  const size_t tokglob = (size_t)b*1024 + hw0 + 16*tt + l15;
  const size_t tbase   = (tokglob >> 5) * 32768;   // 32-token block base in scr16
  const int    t32     = (int)(tokglob & 31);

  for (int cc=0; cc<16; cc++){
    __syncthreads();
    #pragma unroll
    for (int it=0; it<4; it++){
      int e = tid + 512*it;
      int c = e>>5, s = e&31;
      uint4 v = *reinterpret_cast<const uint4*>(cb16 + ((size_t)(cc*64 + c))*CDIM + s*8);
      *reinterpret_cast<uint4*>((char*)cb + c*512 + ((s ^ (c&7))<<4)) = v;
    }
    if (tid < 64) e2s[tid] = e2g[cc*64 + tid];
    __syncthreads();

    f32x4 acc0 = {0.f,0.f,0.f,0.f}, acc1 = {0.f,0.f,0.f,0.f};
    const int c0 = 32*ch2 + l15, c1 = c0 + 16;
    #pragma unroll
    for (int k=0;k<8;k++){
      bf16x8 bf = *reinterpret_cast<const bf16x8*>((const char*)xb + t*512 + (((4*k+g) ^ (t&7))<<4));
      bf16x8 a0 = *reinterpret_cast<const bf16x8*>((const char*)cb + c0*512 + (((4*k+g) ^ (c0&7))<<4));
      bf16x8 a1 = *reinterpret_cast<const bf16x8*>((const char*)cb + c1*512 + (((4*k+g) ^ (c1&7))<<4));
      acc0 = __builtin_amdgcn_mfma_f32_16x16x32_bf16(a0, bf, acc0, 0,0,0);
      acc1 = __builtin_amdgcn_mfma_f32_16x16x32_bf16(a1, bf, acc1, 0,0,0);
    }
    float x2v = x2s[t];
    #pragma unroll
    for (int r=0;r<4;r++){
      int cr0 = 32*ch2 + 4*g + r;
      int cr1 = cr0 + 16;
      scr16[tbase + (size_t)(cc*64 + cr0)*32 + t32] = f2bf(x2v - 2.0f*acc0[r] + e2s[cr0]);
      scr16[tbase + (size_t)(cc*64 + cr1)*32 + t32] = f2bf(x2v - 2.0f*acc1[r] + e2s[cr1]);
    }
  }
}

// ---------- K2: softmax + exact argmin + outputs. FUSE_G2: + zhard + in-block GEMM2 ----------
// 32 tokens/block, grid 2048, LDS 80 KB -> 2 blocks/CU. All global stores = full 128B lines.
// sq input is now a contiguous 64KB stream per block.
template<bool FUSE_G2>
__global__ __launch_bounds__(512, 4) void k2_soft(const float* __restrict__ data,
                                                  const float* __restrict__ centers,
                                                  const unsigned short* __restrict__ ct16,
                                                  const unsigned short* __restrict__ scr16,
                                                  float* __restrict__ out){
  __shared__ unsigned short S[32*1024];   // 64 KB: sq bf16 -> phi bf16; byte = t*2048 + (2c ^ ((t&7)<<4))
  __shared__ unsigned short H[32*256];    // 16 KB: hard bf16 (-> zsoft bf16); byte = t*512 + (2d ^ ((t&7)<<4))

  const int tid = threadIdx.x;
  const int w = tid>>6, lane = tid&63;
  const int l15 = lane&15, g = lane>>4;
  const int tok0 = blockIdx.x*32;
  const int bb = tok0>>10, hw0 = tok0&1023;
  const unsigned short* sqblk = scr16 + (size_t)blockIdx.x*32768;   // contiguous 64KB

  // ---- P0: stream sq (sequential) -> S (transposed, swizzled) ----
  #pragma unroll
  for (int it=0; it<8; it++){
    int e = tid + 512*it;              // 0..4095: c = e>>2, chk = e&3
    int c = e>>2, chk = e&3;
    uint4 v = *reinterpret_cast<const uint4*>(sqblk + (size_t)c*32 + 8*chk);
    const unsigned short* p = (const unsigned short*)&v;
    #pragma unroll
    for (int u=0;u<8;u++){
      int t = 8*chk + u;
      *(unsigned short*)((char*)S + t*2048 + ((2*c) ^ ((t&7)<<4))) = p[u];
    }
  }
  __syncthreads();

  // ---- P1: two passes of 16 tokens: softmax + fp64-refined argmin ----
  for (int p=0;p<2;p++){
    const int t = p*16 + (tid>>5);
    const int j = tid&31;
    const int hb = (lane>=32)?32:0;
    const int tswz = (t&7)<<4;
    char* srow = (char*)S + t*2048;

    float a[32];
    float mns = 3.4e38f;
    #pragma unroll
    for (int i=0;i<32;i++){
      float sp = bf2f(*(const unsigned short*)(srow + ((2*(j+32*i)) ^ tswz)));
      a[i] = sp;
      mns = fminf(mns, sp);
    }
    #pragma unroll
    for (int m=16;m>=1;m>>=1) mns = fminf(mns, __shfl_xor(mns, m));
    float thr = mns + EPS_CAND;
    unsigned cm = 0;
    #pragma unroll
    for (int i=0;i<32;i++) if (a[i] < thr) cm |= (1u<<i);

    double bestd = 1.0e300; int bestk = CNUM;
    const float* xp = data + (size_t)bb*262144 + hw0 + t;
    for(;;){
      unsigned long long bal = __ballot(cm != 0);
      unsigned half = (lane<32)? (unsigned)(bal & 0xffffffffULL) : (unsigned)(bal>>32);
      if (!half) break;
      int src = __ffs(half)-1;
      unsigned cmsrc = (unsigned)__shfl((int)cm, hb + src);
      int ii = __ffs(cmsrc)-1;
      int k = src + 32*ii;
      if (j==src) cm &= ~(1u<<ii);
      double acc = 0.0;
      const float* crow = centers + (size_t)k*CDIM;
      #pragma unroll
      for (int q2=0;q2<8;q2++){
        double xv = (double)xp[(size_t)(j+32*q2)*1024];
        double ev = (double)crow[j+32*q2];
        double df = xv-ev; acc = fma(df,df,acc);
      }
      #pragma unroll
      for (int m=16;m>=1;m>>=1) acc += __shfl_xor(acc, m);
      if (acc < bestd || (acc==bestd && k<bestk)){ bestd=acc; bestk=k; }
    }
    if (j==0) out[OFF_SYM + tok0 + t] = (float)bestk;

    float dmn = sqrtf(fmaxf(mns, 0.f));
    float sum = 0.f;
    #pragma unroll
    for (int i=0;i<32;i++){
      float d = sqrtf(fmaxf(a[i], 0.f));
      a[i] = __expf(dmn - d);
      sum += a[i];
    }
    #pragma unroll
    for (int m=16;m>=1;m>>=1) sum += __shfl_xor(sum, m);
    float rs = 1.f/sum;
    #pragma unroll
    for (int i=0;i<32;i++){
      *(unsigned short*)(srow + ((2*(j+32*i)) ^ tswz)) = f2bf(clamp01(a[i]*rs));
    }
    const float* hrow = centers + (size_t)bestk*CDIM;
    #pragma unroll
    for (int q2=0;q2<8;q2++){
      int c = j + 32*q2;
      *(unsigned short*)((char*)H + t*512 + ((2*c) ^ tswz)) = f2bf(hrow[c]);
    }
  }
  __syncthreads();

  // ---- P2a: phi fp32 stores (full 128B line) ----
  #pragma unroll
  for (int it=0; it<16; ++it){
    int e = tid + 512*it;              // c = e>>3, q = e&7
    int c = e>>3, q = e&7;
    float4 v; float* vp = (float*)&v;
    #pragma unroll
    for (int u=0;u<4;u++){
      int t = 4*q + u;
      vp[u] = bf2f(*(const unsigned short*)((const char*)S + t*2048 + ((2*c) ^ ((t&7)<<4))));
    }
    *reinterpret_cast<float4*>(out + OFF_PHI + (size_t)bb*1048576 + (size_t)c*1024 + hw0 + 4*q) = v;
  }
  // ---- P2b: zbar (+zhard when fused) stores (full 128B line) ----
  #pragma unroll
  for (int it=0; it<4; ++it){
    int e = tid + 512*it;              // d = e>>3, q = e&7
    int d = e>>3, q = e&7;
    float4 v; float* vp = (float*)&v;
    #pragma unroll
    for (int u=0;u<4;u++){
      int t = 4*q + u;
      vp[u] = bf2f(*(const unsigned short*)((const char*)H + t*512 + ((2*d) ^ ((t&7)<<4))));
    }
    size_t base = (size_t)bb*262144 + (size_t)d*1024 + hw0 + 4*q;
    *reinterpret_cast<float4*>(out + OFF_ZBAR + base) = v;
    if (FUSE_G2) *reinterpret_cast<float4*>(out + OFF_ZHARD + base) = v;
  }

  if (FUSE_G2){
    __syncthreads();   // H consumed; S (phi bf16) still intact
    // ---- P3: GEMM2: zsoft^T = ct16 . phi^T ----
    f32x4 z00={0.f,0.f,0.f,0.f}, z01=z00, z10=z00, z11=z00;
    const unsigned short* ar0 = ct16 + (size_t)(16*w + l15)*CNUM;
    const unsigned short* ar1 = ct16 + (size_t)(16*(w+8) + l15)*CNUM;
    const char* br0 = (const char*)S + (size_t)l15*2048;
    const char* br1 = (const char*)S + (size_t)(16+l15)*2048;
    const int bswz = (l15&7)<<4;
    #pragma unroll 8
    for (int s=0;s<32;s++){
      bf16x8 b0 = *reinterpret_cast<const bf16x8*>(br0 + ((64*s + 16*g) ^ bswz));
      bf16x8 b1 = *reinterpret_cast<const bf16x8*>(br1 + ((64*s + 16*g) ^ bswz));
      bf16x8 a0 = *reinterpret_cast<const bf16x8*>(ar0 + 32*s + 8*g);
      bf16x8 a1 = *reinterpret_cast<const bf16x8*>(ar1 + 32*s + 8*g);
      z00 = __builtin_amdgcn_mfma_f32_16x16x32_bf16(a0, b0, z00, 0,0,0);
      z01 = __builtin_amdgcn_mfma_f32_16x16x32_bf16(a0, b1, z01, 0,0,0);
      z10 = __builtin_amdgcn_mfma_f32_16x16x32_bf16(a1, b0, z10, 0,0,0);
      z11 = __builtin_amdgcn_mfma_f32_16x16x32_bf16(a1, b1, z11, 0,0,0);
    }
    #pragma unroll
    for (int mi=0;mi<2;mi++){
      #pragma unroll
      for (int nt=0;nt<2;nt++){
        f32x4 ac = (mi==0) ? (nt==0 ? z00 : z01) : (nt==0 ? z10 : z11);
        int mt = w + 8*mi;
        int t  = nt*16 + l15;
        int d0 = 16*mt + 4*g;
        unsigned short h0,h1;
        unsigned w0,w1;
        h0 = f2bf(clamp11(ac[0])); h1 = f2bf(clamp11(ac[1])); w0 = (unsigned)h0 | ((unsigned)h1<<16);
        h0 = f2bf(clamp11(ac[2])); h1 = f2bf(clamp11(ac[3])); w1 = (unsigned)h0 | ((unsigned)h1<<16);
        *reinterpret_cast<uint2*>((char*)H + t*512 + ((2*d0) ^ ((t&7)<<4))) = make_uint2(w0,w1);
      }
    }
    __syncthreads();
    // ---- P4: zsoft stores (full 128B line) ----
    #pragma unroll
    for (int it=0; it<4; ++it){
      int e = tid + 512*it;
      int d = e>>3, q = e&7;
      float4 v; float* vp = (float*)&v;
      #pragma unroll
      for (int u=0;u<4;u++){
        int t = 4*q + u;
        vp[u] = bf2f(*(const unsigned short*)((const char*)H + t*512 + ((2*d) ^ ((t&7)<<4))));
      }
      *reinterpret_cast<float4*>(out + OFF_ZSOFT + (size_t)bb*262144 + (size_t)d*1024 + hw0 + 4*q) = v;
    }
  }
}

// ---------- K3 (fallback only): GEMM2 from phi fp32 (R7-proven) ----------
__global__ __launch_bounds__(512) void k3_gemm2(const float* __restrict__ phi,
                                                const unsigned short* __restrict__ ct16,
                                                float* __restrict__ zsoft){
  __shared__ unsigned short pls[64*64];
  const int tid = threadIdx.x;
  const int w = tid>>6, lane = tid&63;
  const int l15 = lane&15, g = lane>>4;
  const int b = blockIdx.x>>4, hw0 = (blockIdx.x&15)*64;

  f32x4 acc[2][4];
  #pragma unroll
  for (int h=0;h<2;h++)
    #pragma unroll
    for (int t2=0;t2<4;t2++) acc[h][t2] = (f32x4){0.f,0.f,0.f,0.f};

  for (int ks=0; ks<16; ks++){
    int k0s = ks*64;
    __syncthreads();
    #pragma unroll
    for (int it=0; it<4; it++){
      int e = tid + 512*it;
      int kp = e>>6, t = e&63;
      const float* pp = phi + (size_t)b*1048576 + (size_t)(k0s + 2*kp)*1024 + hw0 + t;
      float v0 = pp[0];
      float v1 = pp[1024];
      unsigned pk = (unsigned)f2bf(v0) | ((unsigned)f2bf(v1)<<16);
      int kk = 2*kp;
      int s = kk>>3;
      *reinterpret_cast<unsigned*>((char*)pls + t*128 + ((s ^ (t&7))<<4) + (kk&7)*2) = pk;
    }
    __syncthreads();
    #pragma unroll
    for (int ki=0; ki<2; ki++){
      int kk0 = k0s + 32*ki;
      bf16x8 a0 = *reinterpret_cast<const bf16x8*>(ct16 + (size_t)(32*w + l15)*CNUM + kk0 + 8*g);
      bf16x8 a1 = *reinterpret_cast<const bf16x8*>(ct16 + (size_t)(32*w + 16 + l15)*CNUM + kk0 + 8*g);
      #pragma unroll
      for (int t2=0;t2<4;t2++){
        int t = 16*t2 + l15;
        bf16x8 bf = *reinterpret_cast<const bf16x8*>((const char*)pls + t*128 + (((4*ki+g) ^ (t&7))<<4));
        acc[0][t2] = __builtin_amdgcn_mfma_f32_16x16x32_bf16(a0, bf, acc[0][t2], 0,0,0);
        acc[1][t2] = __builtin_amdgcn_mfma_f32_16x16x32_bf16(a1, bf, acc[1][t2], 0,0,0);
      }
    }
  }
  #pragma unroll
  for (int h=0;h<2;h++)
    #pragma unroll
    for (int t2=0;t2<4;t2++)
      #pragma unroll
      for (int r=0;r<4;r++){
        int d = 32*w + 16*h + 4*g + r;
        zsoft[(size_t)b*262144 + (size_t)d*1024 + hw0 + 16*t2 + l15] = clamp11(acc[h][t2][r]);
      }
}

extern "C" void kernel_launch(void* const* d_in, const int* in_sizes, int n_in,
                              void* d_out, int out_size, void* d_ws, size_t ws_size,
                              hipStream_t stream) {
  const float* data    = (const float*)d_in[0];
  const float* centers = (const float*)d_in[1];
  float* out           = (float*)d_out;

  const size_t SQ_BYTES = (size_t)1024*65536*2;   // 134,217,728
  const bool wsmode = (ws_size >= SQ_BYTES + 524288 + 524288 + 4096);

  unsigned short *scr16, *cb16, *ct16;
  float *e2;
  if (wsmode){
    scr16 = (unsigned short*)d_ws;
    cb16  = (unsigned short*)((char*)d_ws + SQ_BYTES);
    ct16  = (unsigned short*)((char*)d_ws + SQ_BYTES + 524288);
    e2    = (float*)((char*)d_ws + SQ_BYTES + 1048576);
  } else {
    scr16 = (unsigned short*)(out + OFF_ZSOFT);   // zsoft+zhard as scratch
    cb16  = (unsigned short*)d_ws;
    ct16  = (unsigned short*)((char*)d_ws + 524288);
    e2    = (float*)((char*)d_ws + 1048576);
  }

  prep_convert<<<dim3(256), dim3(256), 0, stream>>>(centers, cb16, ct16);
  prep_e2<<<dim3(4), dim3(256), 0, stream>>>(centers, e2);
  k1_gemm1<<<dim3(1024), dim3(512), 0, stream>>>(data, cb16, e2, scr16);
  if (wsmode){
    k2_soft<true><<<dim3(2048), dim3(512), 0, stream>>>(data, centers, ct16, scr16, out);
  } else {
    k2_soft<false><<<dim3(2048), dim3(512), 0, stream>>>(data, centers, ct16, scr16, out);
    hipMemcpyAsync(out + OFF_ZHARD, out + OFF_ZBAR, (size_t)16777216*4, hipMemcpyDeviceToDevice, stream);
    k3_gemm2<<<dim3(1024), dim3(512), 0, stream>>>(out + OFF_PHI, ct16, out + OFF_ZSOFT);
  }
}